// Round 9
// baseline (262.332 us; speedup 1.0000x reference)
//
#include <hip/hip_runtime.h>

typedef __bf16 bf16;
typedef __bf16 bf16x8 __attribute__((ext_vector_type(8)));
typedef float  f32x4  __attribute__((ext_vector_type(4)));
typedef float  f32x16 __attribute__((ext_vector_type(16)));
typedef int    i32x4  __attribute__((ext_vector_type(4)));
typedef int    i32x16 __attribute__((ext_vector_type(16)));
typedef signed char i8;

#define OC_N   4096
#define IC_K   4096
#define TOKENS 4096
#define KC     256   // outlier K padded to 8x32

// ---------------------------------------------------------------------------
// Fused prep, one block per row r (TOKENS == OC_N == 4096).  UNCHANGED (v5).
// ---------------------------------------------------------------------------
__global__ __launch_bounds__(256) void prep_kernel(
    const float* __restrict__ w, const float* __restrict__ x,
    const float* __restrict__ ow, const int* __restrict__ idx,
    i8* __restrict__ wsgn, i8* __restrict__ xq,
    bf16* __restrict__ xo, bf16* __restrict__ wcorr,
    float* __restrict__ scale_arr, float* __restrict__ sx_arr, int n_out)
{
    __shared__ float red[8];
    const int row = blockIdx.x;
    const int t = threadIdx.x;
    const int lane = t & 63, wv = t >> 6;

    const float4* wr = (const float4*)(w + (size_t)row * IC_K);
    const float4* xr = (const float4*)(x + (size_t)row * IC_K);
    float4 v[4], u[4];
#pragma unroll
    for (int i = 0; i < 4; i++) v[i] = wr[i * 256 + t];
#pragma unroll
    for (int i = 0; i < 4; i++) u[i] = xr[i * 256 + t];

    float xg = 0.f, wg = 0.f, og = 0.f;
    if (t < n_out) {
        const int colg = idx[t];
        xg = x[(size_t)row * IC_K + colg];
        wg = w[(size_t)row * IC_K + colg];
        og = ow[(size_t)row * n_out + t];
    }

    float s = 0.f;
#pragma unroll
    for (int i = 0; i < 4; i++)
        s += v[i].x + v[i].y + v[i].z + v[i].w;
    for (int o = 32; o > 0; o >>= 1) s += __shfl_down(s, o, 64);
    if (lane == 0) red[wv] = s;
    __syncthreads();
    const float mean = (red[0] + red[1] + red[2] + red[3]) * (1.f / IC_K);

    float sa = 0.f;
#pragma unroll
    for (int i = 0; i < 4; i++) {
        sa += fabsf(v[i].x - mean) + fabsf(v[i].y - mean) +
              fabsf(v[i].z - mean) + fabsf(v[i].w - mean);
    }
    for (int o = 32; o > 0; o >>= 1) sa += __shfl_down(sa, o, 64);
    if (lane == 0) red[4 + wv] = sa;
    __syncthreads();
    const float scale = (red[4] + red[5] + red[6] + red[7]) * (1.f / IC_K);

    i8* srow = wsgn + (size_t)row * IC_K;
#pragma unroll
    for (int i = 0; i < 4; i++) {
        float c[4] = { v[i].x - mean, v[i].y - mean, v[i].z - mean, v[i].w - mean };
        char4 q;
        q.x = (i8)((c[0] > 0.f) - (c[0] < 0.f));
        q.y = (i8)((c[1] > 0.f) - (c[1] < 0.f));
        q.z = (i8)((c[2] > 0.f) - (c[2] < 0.f));
        q.w = (i8)((c[3] > 0.f) - (c[3] < 0.f));
        *(char4*)(srow + (size_t)(i * 256 + t) * 4) = q;
    }

    float mx = 0.f;
#pragma unroll
    for (int i = 0; i < 4; i++)
        mx = fmaxf(mx, fmaxf(fmaxf(fabsf(u[i].x), fabsf(u[i].y)),
                             fmaxf(fabsf(u[i].z), fabsf(u[i].w))));
    for (int o = 32; o > 0; o >>= 1) mx = fmaxf(mx, __shfl_down(mx, o, 64));
    if (lane == 0) red[wv] = mx;
    __syncthreads();
    const float maxv = fmaxf(fmaxf(red[0], red[1]), fmaxf(red[2], red[3]));
    const float inv = maxv > 0.f ? 127.f / maxv : 0.f;
    const float sxv = maxv > 0.f ? maxv * (1.f / 127.f) : 1.f;

    i8* xrow = xq + (size_t)row * IC_K;
#pragma unroll
    for (int i = 0; i < 4; i++) {
        char4 q;
        q.x = (i8)(int)rintf(u[i].x * inv);
        q.y = (i8)(int)rintf(u[i].y * inv);
        q.z = (i8)(int)rintf(u[i].z * inv);
        q.w = (i8)(int)rintf(u[i].w * inv);
        *(char4*)(xrow + (size_t)(i * 256 + t) * 4) = q;
    }
    if (t == 0) { scale_arr[row] = scale; sx_arr[row] = sxv; }

    if (t < n_out) {
        xo[(size_t)row * KC + t] = (bf16)xg;
        const float wc_ = wg - mean;
        const float sg = (wc_ > 0.f) ? 1.f : ((wc_ < 0.f) ? -1.f : 0.f);
        wcorr[(size_t)row * KC + t] = (bf16)(og - scale * sg);
    } else if (t < KC) {
        xo[(size_t)row * KC + t] = (bf16)0.f;
        wcorr[(size_t)row * KC + t] = (bf16)0.f;
    }
}

// ---------------------------------------------------------------------------
// GEMM v8: v5 + ONE-PHASE-DEEP REGISTER PIPELINE of operand fragments.
// ERRATUM of v7 comment: occupancy is LDS-bound (160KB = 1 blk/CU = 2
// waves/SIMD); per-SIMD reg pool 2048 -> ~1024 regs/wave available, we
// used 256.  Doubling the fragment set (+48 VGPR) is free.
// v5 wall ~2420cy/phase vs LDS pipe ~1790, MFMA ~1170: the ~600cy gap is
// post-barrier ds_read->MFMA latency in 2-wave lockstep.  v8 removes it:
// two named fragment sets A/B (static indexing, rule #20); per phase:
//   VMCNT(8); BAR; stage(c+4); reads(c+1)->other; MFMA(current)
// MFMAs issue from registers immediately post-barrier; the 12 ds_reads of
// phase c+1 overlap the MFMA cluster of phase c within each wave.
// Ledger (4 loads/chunk): VMCNT(8) at end of iter c -> landed 4(c+3) ->
// chunks <= c+2 resident (covers next iter's reads(c+2)).  Prologue:
// stage(0..3), VMCNT(8) -> chunks 0,1 resident, reads(0).  Tail waits
// 8/8/4/0 retire chunks 60..63 (counts in-line below).
// WAR: reads slot (c+1)%5 vs stage slot (c+4)%5 -> distance 3, disjoint.
// stage(c+4) rewrites chunk c-1's slot, last read in iter c-2 -> two
// barriers in between.  RAW cross-wave: VMCNT(8)+BAR publishes chunk c+1
// before any wave reads it (per-wave in-order vmcnt retirement).
// Same pipeline on the bf16 corr loop (8 chunks, VMCNT(4) steady).
// Numerics: pure reorder -> absmax must stay bit-identical (0.0546875).
// ---------------------------------------------------------------------------
__device__ __forceinline__ void gload16(const void* g, void* l)
{
    __builtin_amdgcn_global_load_lds(
        (const __attribute__((address_space(1))) void*)g,
        (__attribute__((address_space(3))) void*)l, 16, 0, 0);
}

#define VMCNT(n) asm volatile("s_waitcnt vmcnt(" #n ")" ::: "memory")
#define SCHED0   __builtin_amdgcn_sched_barrier(0)
#define BAR      __builtin_amdgcn_s_barrier()

__global__ __launch_bounds__(512, 2) void gemm_kernel(
    const i8* __restrict__ A, const i8* __restrict__ B,
    const bf16* __restrict__ Axo, const bf16* __restrict__ Bwc,
    const float* __restrict__ sx, const float* __restrict__ scale,
    const float* __restrict__ bias, float* __restrict__ C)
{
    constexpr int K = IC_K, N = OC_N;
    __shared__ __align__(16) i8 ring[5][2][16384];   // 160 KB (full pool)

    const int tid  = threadIdx.x;
    const int lane = tid & 63;
    const int wave = tid >> 6;
    const int wm = wave >> 2, wn = wave & 3;          // 2 (M) x 4 (N) waves
    const int m32 = lane & 31, kg = lane >> 5;

    // XCD-aware 4x8 rectangle per XCD (bijective; 256 blocks, 8 XCDs)
    const int bid = blockIdx.x;
    const int xcd = bid & 7, tix = bid >> 3;
    const int bm = (xcd >> 1) * 4 + (tix & 3);
    const int bn = (xcd & 1) * 8 + (tix >> 2);

    // ---- staging map: LDS quad Q = tid (+512) -> (row, swizzled qk) ----
    const int Q0 = tid, Q1 = 512 + tid;
    const int r0 = Q0 >> 2, r1 = Q1 >> 2;
    const int q0 = (Q0 & 3) ^ ((r0 >> 1) & 3);
    const int q1 = (Q1 & 3) ^ ((r1 >> 1) & 3);
    const int d0 = Q0 * 16, d1 = Q1 * 16;

    const i8* gA0 = A + (size_t)(bm * 256 + r0) * K + q0 * 16;
    const i8* gA1 = A + (size_t)(bm * 256 + r1) * K + q1 * 16;
    const i8* gB0 = B + (size_t)(bn * 256 + r0) * K + q0 * 16;
    const i8* gB1 = B + (size_t)(bn * 256 + r1) * K + q1 * 16;

    auto stage = [&](int c) {
        i8* bs = &ring[c % 5][0][0];
        const int ko = c * 64;
        gload16(gA0 + ko, bs + d0);
        gload16(gA1 + ko, bs + d1);
        gload16(gB0 + ko, bs + 16384 + d0);
        gload16(gB1 + ko, bs + 16384 + d1);
    };

    // ---- per-lane ds_read byte offsets (shared by i8 and bf16 loops) ----
    int offA[4][2], offB[2][2];
#pragma unroll
    for (int mi = 0; mi < 4; ++mi) {
        const int r = wm * 128 + mi * 32 + m32;
#pragma unroll
        for (int ks = 0; ks < 2; ++ks)
            offA[mi][ks] = r * 64 + ((ks * 2 + kg) ^ ((r >> 1) & 3)) * 16;
    }
#pragma unroll
    for (int ni = 0; ni < 2; ++ni) {
        const int r = wn * 64 + ni * 32 + m32;
#pragma unroll
        for (int ks = 0; ks < 2; ++ks)
            offB[ni][ks] = r * 64 + ((ks * 2 + kg) ^ ((r >> 1) & 3)) * 16;
    }

    i32x16 acc[4][2] = {};

    auto reads_i8 = [&](int c, i32x4 (&af)[4][2], i32x4 (&bfr)[2][2]) {
        const i8* sA = &ring[c % 5][0][0];
        const i8* sB = sA + 16384;
#pragma unroll
        for (int mi = 0; mi < 4; ++mi)
#pragma unroll
            for (int ks = 0; ks < 2; ++ks)
                af[mi][ks] = *(const i32x4*)(sA + offA[mi][ks]);
#pragma unroll
        for (int ni = 0; ni < 2; ++ni)
#pragma unroll
            for (int ks = 0; ks < 2; ++ks)
                bfr[ni][ks] = *(const i32x4*)(sB + offB[ni][ks]);
    };
    auto mfma_i8 = [&](i32x4 (&af)[4][2], i32x4 (&bfr)[2][2]) {
        __builtin_amdgcn_s_setprio(1);
#pragma unroll
        for (int ks = 0; ks < 2; ++ks)
#pragma unroll
            for (int mi = 0; mi < 4; ++mi)
#pragma unroll
                for (int ni = 0; ni < 2; ++ni)
                    acc[mi][ni] = __builtin_amdgcn_mfma_i32_32x32x32_i8(
                        af[mi][ks], bfr[ni][ks], acc[mi][ni], 0, 0, 0);
        __builtin_amdgcn_s_setprio(0);
    };

    // ---- main i8 loop: reg-pipelined, two named fragment sets ----
    i32x4 afA[4][2], bfrA[2][2], afB[4][2], bfrB[2][2];

    stage(0); stage(1); stage(2); stage(3);
    VMCNT(8); BAR; SCHED0;          // chunks 0,1 resident
    reads_i8(0, afA, bfrA);

    for (int c = 0; c < 58; c += 2) {
        // body 1: mfma chunk c, prefetch frags c+1
        stage(c + 4); SCHED0;
        reads_i8(c + 1, afB, bfrB);
        mfma_i8(afA, bfrA);
        VMCNT(8); BAR; SCHED0;      // chunks <= c+2 resident
        // body 2: mfma chunk c+1, prefetch frags c+2
        stage(c + 5); SCHED0;
        reads_i8(c + 2, afA, bfrA);
        mfma_i8(afB, bfrB);
        VMCNT(8); BAR; SCHED0;      // chunks <= c+3 resident
    }
    // tail: A = frags(58); staged <= 61; chunks <= 59 resident
    stage(62); SCHED0; reads_i8(59, afB, bfrB); mfma_i8(afA, bfrA);
    VMCNT(8); BAR; SCHED0;          // issued 252 -> chunks <= 60
    stage(63); SCHED0; reads_i8(60, afA, bfrA); mfma_i8(afB, bfrB);
    VMCNT(8); BAR; SCHED0;          // issued 256 -> chunks <= 61
    reads_i8(61, afB, bfrB); mfma_i8(afA, bfrA);
    VMCNT(4); BAR; SCHED0;          // chunks <= 62
    reads_i8(62, afA, bfrA); mfma_i8(afB, bfrB);
    VMCNT(0); BAR; SCHED0;          // all chunks resident
    reads_i8(63, afB, bfrB); mfma_i8(afA, bfrA);
    mfma_i8(afB, bfrB);

    // ---- i32 -> f32 scaling (32x32 C layout: row=(r&3)+8*(r>>2)+4*kg) ----
    const int rbase = bm * 256 + wm * 128 + 4 * kg;
    const int cbase = bn * 256 + wn * 64 + m32;
    float scl2[2], bv2[2];
#pragma unroll
    for (int ni = 0; ni < 2; ++ni) {
        scl2[ni] = scale[cbase + ni * 32];
        bv2[ni]  = bias[cbase + ni * 32];
    }
    f32x16 facc[4][2];
#pragma unroll
    for (int mi = 0; mi < 4; ++mi)
#pragma unroll
        for (int r = 0; r < 16; ++r) {
            const float sxv = sx[rbase + mi * 32 + (r & 3) + 8 * (r >> 2)];
#pragma unroll
            for (int ni = 0; ni < 2; ++ni)
                facc[mi][ni][r] = (float)acc[mi][ni][r] * sxv * scl2[ni];
        }
    // drain scalar loads (exact corr vmcnt counts); publish i8-phase reads
    asm volatile("s_waitcnt vmcnt(0)" ::: "memory");
    BAR;

    // ---- bf16 correction: 8 chunks of K=32, same reg-pipelined schedule ----
    const i8* cA0 = (const i8*)Axo + (size_t)(bm * 256 + r0) * (KC * 2) + q0 * 16;
    const i8* cA1 = (const i8*)Axo + (size_t)(bm * 256 + r1) * (KC * 2) + q1 * 16;
    const i8* cB0 = (const i8*)Bwc + (size_t)(bn * 256 + r0) * (KC * 2) + q0 * 16;
    const i8* cB1 = (const i8*)Bwc + (size_t)(bn * 256 + r1) * (KC * 2) + q1 * 16;
    auto stagec = [&](int c) {
        i8* bs = &ring[c % 5][0][0];
        const int ko = c * 64;
        gload16(cA0 + ko, bs + d0);
        gload16(cA1 + ko, bs + d1);
        gload16(cB0 + ko, bs + 16384 + d0);
        gload16(cB1 + ko, bs + 16384 + d1);
    };
    auto reads_bf = [&](int c, bf16x8 (&af)[4][2], bf16x8 (&bfr)[2][2]) {
        const i8* sA = &ring[c % 5][0][0];
        const i8* sB = sA + 16384;
#pragma unroll
        for (int mi = 0; mi < 4; ++mi)
#pragma unroll
            for (int ks = 0; ks < 2; ++ks)
                af[mi][ks] = *(const bf16x8*)(sA + offA[mi][ks]);
#pragma unroll
        for (int ni = 0; ni < 2; ++ni)
#pragma unroll
            for (int ks = 0; ks < 2; ++ks)
                bfr[ni][ks] = *(const bf16x8*)(sB + offB[ni][ks]);
    };
    auto mfma_bf = [&](bf16x8 (&af)[4][2], bf16x8 (&bfr)[2][2]) {
        __builtin_amdgcn_s_setprio(1);
#pragma unroll
        for (int ks = 0; ks < 2; ++ks)
#pragma unroll
            for (int mi = 0; mi < 4; ++mi)
#pragma unroll
                for (int ni = 0; ni < 2; ++ni)
                    facc[mi][ni] = __builtin_amdgcn_mfma_f32_32x32x16_bf16(
                        af[mi][ks], bfr[ni][ks], facc[mi][ni], 0, 0, 0);
        __builtin_amdgcn_s_setprio(0);
    };

    // corr ledger (4 loads/chunk): prologue stagec(0..2)=12 issued,
    // VMCNT(4) -> landed 8 = chunks 0,1 resident.  Iter c: stagec(c+3);
    // VMCNT(4) at end -> landed 4(c+3) -> chunks <= c+2.  WAR: reads slot
    // (c+1)%5 vs stagec slot (c+3)%5 disjoint (dist 2); stagec(c+3)
    // rewrites chunk c-2's slot, last read iter c-3 -> >=2 barriers.
    bf16x8 cfA[4][2], cgA[2][2], cfB[4][2], cgB[2][2];
    stagec(0); stagec(1); stagec(2);
    VMCNT(4); BAR; SCHED0;          // chunks 0,1 resident
    reads_bf(0, cfA, cgA);

    for (int c = 0; c < 4; c += 2) {
        stagec(c + 3); SCHED0;
        reads_bf(c + 1, cfB, cgB);
        mfma_bf(cfA, cgA);
        VMCNT(4); BAR; SCHED0;      // chunks <= c+2
        stagec(c + 4); SCHED0;
        reads_bf(c + 2, cfA, cgA);
        mfma_bf(cfB, cgB);
        VMCNT(4); BAR; SCHED0;      // chunks <= c+3
    }
    // tail: A = frags(4); staged <= 6; chunks <= 5 resident
    stagec(7); SCHED0; reads_bf(5, cfB, cgB); mfma_bf(cfA, cgA);
    VMCNT(4); BAR; SCHED0;          // issued 32 -> chunks <= 6
    reads_bf(6, cfA, cgA); mfma_bf(cfB, cgB);
    VMCNT(0); BAR; SCHED0;          // all
    reads_bf(7, cfB, cgB); mfma_bf(cfA, cgA);
    mfma_bf(cfB, cgB);

    // ---- epilogue: + bias, store ----
#pragma unroll
    for (int mi = 0; mi < 4; ++mi)
#pragma unroll
        for (int r = 0; r < 16; ++r) {
            const int row = rbase + mi * 32 + (r & 3) + 8 * (r >> 2);
#pragma unroll
            for (int ni = 0; ni < 2; ++ni)
                C[(size_t)row * N + cbase + ni * 32] = facc[mi][ni][r] + bv2[ni];
        }
}

// ---------------------------------------------------------------------------
extern "C" void kernel_launch(void* const* d_in, const int* in_sizes, int n_in,
                              void* d_out, int out_size, void* d_ws, size_t ws_size,
                              hipStream_t stream)
{
    const float* x    = (const float*)d_in[0];
    const float* w    = (const float*)d_in[1];
    const float* bias = (const float*)d_in[2];
    const float* ow   = (const float*)d_in[3];
    const int*   idx  = (const int*)d_in[4];
    const int    n_out = in_sizes[4];
    float* out = (float*)d_out;

    char* ws = (char*)d_ws;
    i8*    xq    = (i8*)ws;                                   // 16 MB
    i8*    wsgn  = (i8*)(ws + (size_t)16 * 1024 * 1024);      // 16 MB
    bf16*  xo    = (bf16*)(ws + (size_t)32 * 1024 * 1024);    // 2 MB
    bf16*  wcorr = (bf16*)(ws + (size_t)34 * 1024 * 1024);    // 2 MB
    float* sx    = (float*)(ws + (size_t)36 * 1024 * 1024);   // 16 KB
    float* scl   = (float*)(ws + (size_t)36 * 1024 * 1024 + 16 * 1024); // 16 KB

    hipLaunchKernelGGL(prep_kernel, dim3(OC_N), dim3(256), 0, stream,
                       w, x, ow, idx, wsgn, xq, xo, wcorr, scl, sx, n_out);
    hipLaunchKernelGGL(gemm_kernel, dim3(256), dim3(512), 0, stream,
                       xq, wsgn, xo, wcorr, sx, scl, bias, out);
}

// Round 10
// 252.402 us; speedup vs baseline: 1.0393x; 1.0393x over previous
//
#include <hip/hip_runtime.h>

typedef __bf16 bf16;
typedef __bf16 bf16x8 __attribute__((ext_vector_type(8)));
typedef float  f32x4  __attribute__((ext_vector_type(4)));
typedef float  f32x16 __attribute__((ext_vector_type(16)));
typedef int    i32x4  __attribute__((ext_vector_type(4)));
typedef int    i32x16 __attribute__((ext_vector_type(16)));
typedef signed char i8;

#define OC_N   4096
#define IC_K   4096
#define TOKENS 4096
#define KC     256   // outlier K padded to 8x32

// ---------------------------------------------------------------------------
// Fused prep, one block per row r (TOKENS == OC_N == 4096).  (v5 version)
// ---------------------------------------------------------------------------
__global__ __launch_bounds__(256) void prep_kernel(
    const float* __restrict__ w, const float* __restrict__ x,
    const float* __restrict__ ow, const int* __restrict__ idx,
    i8* __restrict__ wsgn, i8* __restrict__ xq,
    bf16* __restrict__ xo, bf16* __restrict__ wcorr,
    float* __restrict__ scale_arr, float* __restrict__ sx_arr, int n_out)
{
    __shared__ float red[8];
    const int row = blockIdx.x;
    const int t = threadIdx.x;
    const int lane = t & 63, wv = t >> 6;

    const float4* wr = (const float4*)(w + (size_t)row * IC_K);
    const float4* xr = (const float4*)(x + (size_t)row * IC_K);
    float4 v[4], u[4];
#pragma unroll
    for (int i = 0; i < 4; i++) v[i] = wr[i * 256 + t];
#pragma unroll
    for (int i = 0; i < 4; i++) u[i] = xr[i * 256 + t];

    float xg = 0.f, wg = 0.f, og = 0.f;
    if (t < n_out) {
        const int colg = idx[t];
        xg = x[(size_t)row * IC_K + colg];
        wg = w[(size_t)row * IC_K + colg];
        og = ow[(size_t)row * n_out + t];
    }

    float s = 0.f;
#pragma unroll
    for (int i = 0; i < 4; i++)
        s += v[i].x + v[i].y + v[i].z + v[i].w;
    for (int o = 32; o > 0; o >>= 1) s += __shfl_down(s, o, 64);
    if (lane == 0) red[wv] = s;
    __syncthreads();
    const float mean = (red[0] + red[1] + red[2] + red[3]) * (1.f / IC_K);

    float sa = 0.f;
#pragma unroll
    for (int i = 0; i < 4; i++) {
        sa += fabsf(v[i].x - mean) + fabsf(v[i].y - mean) +
              fabsf(v[i].z - mean) + fabsf(v[i].w - mean);
    }
    for (int o = 32; o > 0; o >>= 1) sa += __shfl_down(sa, o, 64);
    if (lane == 0) red[4 + wv] = sa;
    __syncthreads();
    const float scale = (red[4] + red[5] + red[6] + red[7]) * (1.f / IC_K);

    i8* srow = wsgn + (size_t)row * IC_K;
#pragma unroll
    for (int i = 0; i < 4; i++) {
        float c[4] = { v[i].x - mean, v[i].y - mean, v[i].z - mean, v[i].w - mean };
        char4 q;
        q.x = (i8)((c[0] > 0.f) - (c[0] < 0.f));
        q.y = (i8)((c[1] > 0.f) - (c[1] < 0.f));
        q.z = (i8)((c[2] > 0.f) - (c[2] < 0.f));
        q.w = (i8)((c[3] > 0.f) - (c[3] < 0.f));
        *(char4*)(srow + (size_t)(i * 256 + t) * 4) = q;
    }

    float mx = 0.f;
#pragma unroll
    for (int i = 0; i < 4; i++)
        mx = fmaxf(mx, fmaxf(fmaxf(fabsf(u[i].x), fabsf(u[i].y)),
                             fmaxf(fabsf(u[i].z), fabsf(u[i].w))));
    for (int o = 32; o > 0; o >>= 1) mx = fmaxf(mx, __shfl_down(mx, o, 64));
    if (lane == 0) red[wv] = mx;
    __syncthreads();
    const float maxv = fmaxf(fmaxf(red[0], red[1]), fmaxf(red[2], red[3]));
    const float inv = maxv > 0.f ? 127.f / maxv : 0.f;
    const float sxv = maxv > 0.f ? maxv * (1.f / 127.f) : 1.f;

    i8* xrow = xq + (size_t)row * IC_K;
#pragma unroll
    for (int i = 0; i < 4; i++) {
        char4 q;
        q.x = (i8)(int)rintf(u[i].x * inv);
        q.y = (i8)(int)rintf(u[i].y * inv);
        q.z = (i8)(int)rintf(u[i].z * inv);
        q.w = (i8)(int)rintf(u[i].w * inv);
        *(char4*)(xrow + (size_t)(i * 256 + t) * 4) = q;
    }
    if (t == 0) { scale_arr[row] = scale; sx_arr[row] = sxv; }

    if (t < n_out) {
        xo[(size_t)row * KC + t] = (bf16)xg;
        const float wc_ = wg - mean;
        const float sg = (wc_ > 0.f) ? 1.f : ((wc_ < 0.f) ? -1.f : 0.f);
        wcorr[(size_t)row * KC + t] = (bf16)(og - scale * sg);
    } else if (t < KC) {
        xo[(size_t)row * KC + t] = (bf16)0.f;
        wcorr[(size_t)row * KC + t] = (bf16)0.f;
    }
}

// ---------------------------------------------------------------------------
// GEMM v9 == v5 (measured best, twice: gemm 83.0/85.8us, total 251.95us).
// FINAL STRUCTURAL BOX (all walls measured):
//  - v6 (2-bit packed B): FETCH 56->31MB as modeled but +80 VALU/phase on
//    the MFMA critical path -> 98.5us.  Traffic cuts that add critical-
//    path VALU regress.
//  - v8 (reg-pipelined fragments): 256-reg/wave cap at 2-wave/SIMD is
//    HARD (VGPR_Count pinned at 128+128AGPR; compiler honored
//    launch_bounds(512,2) and spilled: WRITE 66.5->85.5MB, FETCH
//    55.5->64.5MB scratch traffic) -> 98us.
//  - conflicts pinned at exactly 7,077,888 (= 96 b128-reads x 4cy x 72
//    phases x 256 CU) across v2-v5 regardless of order/swizzle:
//    deterministic read-pattern tax, not schedulable.
//  - pipes/phase: MFMA 1170cy (µbench i8 ceiling), LDS 1540-1790cy
//    (binding), wall ~2420cy; residual = cross-pipe dependency slack
//    irreducible at 2 waves/SIMD with zero spare registers.
// Structure: 256x256 tile, 8 waves (2Mx4N), depth-5 LDS ring (160KB),
// ONE barrier/phase, reads-first body, XCD-aware 4x8 tiling, counted
// vmcnt (never 0 in steady state), setprio around MFMA clusters.
// ---------------------------------------------------------------------------
__device__ __forceinline__ void gload16(const void* g, void* l)
{
    __builtin_amdgcn_global_load_lds(
        (const __attribute__((address_space(1))) void*)g,
        (__attribute__((address_space(3))) void*)l, 16, 0, 0);
}

#define VMCNT(n) asm volatile("s_waitcnt vmcnt(" #n ")" ::: "memory")
#define SCHED0   __builtin_amdgcn_sched_barrier(0)
#define BAR      __builtin_amdgcn_s_barrier()

__global__ __launch_bounds__(512, 2) void gemm_kernel(
    const i8* __restrict__ A, const i8* __restrict__ B,
    const bf16* __restrict__ Axo, const bf16* __restrict__ Bwc,
    const float* __restrict__ sx, const float* __restrict__ scale,
    const float* __restrict__ bias, float* __restrict__ C)
{
    constexpr int K = IC_K, N = OC_N;
    __shared__ __align__(16) i8 ring[5][2][16384];   // 160 KB (full pool)

    const int tid  = threadIdx.x;
    const int lane = tid & 63;
    const int wave = tid >> 6;
    const int wm = wave >> 2, wn = wave & 3;          // 2 (M) x 4 (N) waves
    const int m32 = lane & 31, kg = lane >> 5;

    // XCD-aware 4x8 rectangle per XCD (bijective; 256 blocks, 8 XCDs)
    const int bid = blockIdx.x;
    const int xcd = bid & 7, tix = bid >> 3;          // 32 tiles per XCD
    const int bm = (xcd >> 1) * 4 + (tix & 3);        // 16 values
    const int bn = (xcd & 1) * 8 + (tix >> 2);        // 16 values

    // ---- staging map: LDS quad Q = tid (+512) -> (row, swizzled qk) ----
    const int Q0 = tid, Q1 = 512 + tid;
    const int r0 = Q0 >> 2, r1 = Q1 >> 2;
    const int q0 = (Q0 & 3) ^ ((r0 >> 1) & 3);
    const int q1 = (Q1 & 3) ^ ((r1 >> 1) & 3);
    const int d0 = Q0 * 16, d1 = Q1 * 16;

    const i8* gA0 = A + (size_t)(bm * 256 + r0) * K + q0 * 16;
    const i8* gA1 = A + (size_t)(bm * 256 + r1) * K + q1 * 16;
    const i8* gB0 = B + (size_t)(bn * 256 + r0) * K + q0 * 16;
    const i8* gB1 = B + (size_t)(bn * 256 + r1) * K + q1 * 16;

    auto stage = [&](int c) {
        i8* bs = &ring[c % 5][0][0];
        const int ko = c * 64;
        gload16(gA0 + ko, bs + d0);
        gload16(gA1 + ko, bs + d1);
        gload16(gB0 + ko, bs + 16384 + d0);
        gload16(gB1 + ko, bs + 16384 + d1);
    };

    // ---- per-lane ds_read byte offsets (shared by i8 and bf16 loops) ----
    int offA[4][2], offB[2][2];
#pragma unroll
    for (int mi = 0; mi < 4; ++mi) {
        const int r = wm * 128 + mi * 32 + m32;
#pragma unroll
        for (int ks = 0; ks < 2; ++ks)
            offA[mi][ks] = r * 64 + ((ks * 2 + kg) ^ ((r >> 1) & 3)) * 16;
    }
#pragma unroll
    for (int ni = 0; ni < 2; ++ni) {
        const int r = wn * 64 + ni * 32 + m32;
#pragma unroll
        for (int ks = 0; ks < 2; ++ks)
            offB[ni][ks] = r * 64 + ((ks * 2 + kg) ^ ((r >> 1) & 3)) * 16;
    }

    i32x16 acc[4][2] = {};

    auto reads_i8 = [&](int c, i32x4 (&af)[4][2], i32x4 (&bfr)[2][2]) {
        const i8* sA = &ring[c % 5][0][0];
        const i8* sB = sA + 16384;
#pragma unroll
        for (int mi = 0; mi < 4; ++mi)
#pragma unroll
            for (int ks = 0; ks < 2; ++ks)
                af[mi][ks] = *(const i32x4*)(sA + offA[mi][ks]);
#pragma unroll
        for (int ni = 0; ni < 2; ++ni)
#pragma unroll
            for (int ks = 0; ks < 2; ++ks)
                bfr[ni][ks] = *(const i32x4*)(sB + offB[ni][ks]);
    };
    auto mfma_i8 = [&](i32x4 (&af)[4][2], i32x4 (&bfr)[2][2]) {
        __builtin_amdgcn_s_setprio(1);
#pragma unroll
        for (int ks = 0; ks < 2; ++ks)
#pragma unroll
            for (int mi = 0; mi < 4; ++mi)
#pragma unroll
                for (int ni = 0; ni < 2; ++ni)
                    acc[mi][ni] = __builtin_amdgcn_mfma_i32_32x32x32_i8(
                        af[mi][ks], bfr[ni][ks], acc[mi][ni], 0, 0, 0);
        __builtin_amdgcn_s_setprio(0);
    };

    // ---- main i8 loop: 64 chunks, depth 5, one barrier, reads-first ----
    stage(0); stage(1); stage(2); stage(3);
#pragma unroll 5
    for (int c = 0; c < 60; ++c) {
        VMCNT(12); BAR; SCHED0;
        i32x4 af[4][2], bfr[2][2];
        reads_i8(c, af, bfr);
        SCHED0;
        stage(c + 4);
        SCHED0;
        mfma_i8(af, bfr);
    }
    {
        i32x4 af[4][2], bfr[2][2];
        VMCNT(12); BAR; SCHED0; reads_i8(60, af, bfr); SCHED0; mfma_i8(af, bfr);
        VMCNT(8);  BAR; SCHED0; reads_i8(61, af, bfr); SCHED0; mfma_i8(af, bfr);
        VMCNT(4);  BAR; SCHED0; reads_i8(62, af, bfr); SCHED0; mfma_i8(af, bfr);
        VMCNT(0);  BAR; SCHED0; reads_i8(63, af, bfr); SCHED0; mfma_i8(af, bfr);
    }

    // ---- i32 -> f32 scaling (32x32 C layout: row=(r&3)+8*(r>>2)+4*kg) ----
    const int rbase = bm * 256 + wm * 128 + 4 * kg;
    const int cbase = bn * 256 + wn * 64 + m32;
    float scl2[2], bv2[2];
#pragma unroll
    for (int ni = 0; ni < 2; ++ni) {
        scl2[ni] = scale[cbase + ni * 32];
        bv2[ni]  = bias[cbase + ni * 32];
    }
    f32x16 facc[4][2];
#pragma unroll
    for (int mi = 0; mi < 4; ++mi)
#pragma unroll
        for (int r = 0; r < 16; ++r) {
            const float sxv = sx[rbase + mi * 32 + (r & 3) + 8 * (r >> 2)];
#pragma unroll
            for (int ni = 0; ni < 2; ++ni)
                facc[mi][ni][r] = (float)acc[mi][ni][r] * sxv * scl2[ni];
        }
    // drain sx/scale/bias loads (exact vmcnt counts for corr loop) and
    // barrier: all waves' i8-phase LDS reads are done before slot reuse.
    asm volatile("s_waitcnt vmcnt(0)" ::: "memory");
    BAR;

    // ---- bf16 correction: 8 chunks of K=32 over KC=256, same schedule ----
    const i8* cA0 = (const i8*)Axo + (size_t)(bm * 256 + r0) * (KC * 2) + q0 * 16;
    const i8* cA1 = (const i8*)Axo + (size_t)(bm * 256 + r1) * (KC * 2) + q1 * 16;
    const i8* cB0 = (const i8*)Bwc + (size_t)(bn * 256 + r0) * (KC * 2) + q0 * 16;
    const i8* cB1 = (const i8*)Bwc + (size_t)(bn * 256 + r1) * (KC * 2) + q1 * 16;
    auto stagec = [&](int c) {
        i8* bs = &ring[c % 5][0][0];
        const int ko = c * 64;
        gload16(cA0 + ko, bs + d0);
        gload16(cA1 + ko, bs + d1);
        gload16(cB0 + ko, bs + 16384 + d0);
        gload16(cB1 + ko, bs + 16384 + d1);
    };
    auto reads_bf = [&](int c, bf16x8 (&af)[4][2], bf16x8 (&bfr)[2][2]) {
        const i8* sA = &ring[c % 5][0][0];
        const i8* sB = sA + 16384;
#pragma unroll
        for (int mi = 0; mi < 4; ++mi)
#pragma unroll
            for (int ks = 0; ks < 2; ++ks)
                af[mi][ks] = *(const bf16x8*)(sA + offA[mi][ks]);
#pragma unroll
        for (int ni = 0; ni < 2; ++ni)
#pragma unroll
            for (int ks = 0; ks < 2; ++ks)
                bfr[ni][ks] = *(const bf16x8*)(sB + offB[ni][ks]);
    };
    auto mfma_bf = [&](bf16x8 (&af)[4][2], bf16x8 (&bfr)[2][2]) {
        __builtin_amdgcn_s_setprio(1);
#pragma unroll
        for (int ks = 0; ks < 2; ++ks)
#pragma unroll
            for (int mi = 0; mi < 4; ++mi)
#pragma unroll
                for (int ni = 0; ni < 2; ++ni)
                    facc[mi][ni] = __builtin_amdgcn_mfma_f32_32x32x16_bf16(
                        af[mi][ks], bfr[ni][ks], facc[mi][ni], 0, 0, 0);
        __builtin_amdgcn_s_setprio(0);
    };

    stagec(0); stagec(1); stagec(2);
#pragma unroll
    for (int c = 0; c < 5; ++c) {
        VMCNT(8); BAR; SCHED0;
        bf16x8 af[4][2], bfr[2][2];
        reads_bf(c, af, bfr);
        SCHED0;
        stagec(c + 3);
        SCHED0;
        mfma_bf(af, bfr);
    }
    {
        bf16x8 af[4][2], bfr[2][2];
        VMCNT(8); BAR; SCHED0; reads_bf(5, af, bfr); SCHED0; mfma_bf(af, bfr);
        VMCNT(4); BAR; SCHED0; reads_bf(6, af, bfr); SCHED0; mfma_bf(af, bfr);
        VMCNT(0); BAR; SCHED0; reads_bf(7, af, bfr); SCHED0; mfma_bf(af, bfr);
    }

    // ---- epilogue: + bias, store ----
#pragma unroll
    for (int mi = 0; mi < 4; ++mi)
#pragma unroll
        for (int r = 0; r < 16; ++r) {
            const int row = rbase + mi * 32 + (r & 3) + 8 * (r >> 2);
#pragma unroll
            for (int ni = 0; ni < 2; ++ni)
                C[(size_t)row * N + cbase + ni * 32] = facc[mi][ni][r] + bv2[ni];
        }
}

// ---------------------------------------------------------------------------
extern "C" void kernel_launch(void* const* d_in, const int* in_sizes, int n_in,
                              void* d_out, int out_size, void* d_ws, size_t ws_size,
                              hipStream_t stream)
{
    const float* x    = (const float*)d_in[0];
    const float* w    = (const float*)d_in[1];
    const float* bias = (const float*)d_in[2];
    const float* ow   = (const float*)d_in[3];
    const int*   idx  = (const int*)d_in[4];
    const int    n_out = in_sizes[4];
    float* out = (float*)d_out;

    char* ws = (char*)d_ws;
    i8*    xq    = (i8*)ws;                                   // 16 MB
    i8*    wsgn  = (i8*)(ws + (size_t)16 * 1024 * 1024);      // 16 MB
    bf16*  xo    = (bf16*)(ws + (size_t)32 * 1024 * 1024);    // 2 MB
    bf16*  wcorr = (bf16*)(ws + (size_t)34 * 1024 * 1024);    // 2 MB
    float* sx    = (float*)(ws + (size_t)36 * 1024 * 1024);   // 16 KB
    float* scl   = (float*)(ws + (size_t)36 * 1024 * 1024 + 16 * 1024); // 16 KB

    hipLaunchKernelGGL(prep_kernel, dim3(OC_N), dim3(256), 0, stream,
                       w, x, ow, idx, wsgn, xq, xo, wcorr, scl, sx, n_out);
    hipLaunchKernelGGL(gemm_kernel, dim3(256), dim3(512), 0, stream,
                       xq, wsgn, xo, wcorr, sx, scl, bias, out);
}